// Round 1
// baseline (29.958 us; speedup 1.0000x reference)
//
#include <hip/hip_runtime.h>

#define EPS 1e-6f

__global__ __launch_bounds__(256) void iou_loss_kernel(
    const float2* __restrict__ pred4,  // layer-4 base, (B, N) float2
    const float2* __restrict__ gt4,    // layer-4 base, (B, T) float2
    const int* __restrict__ bs_ptr,
    float* __restrict__ out)
{
    __shared__ float2 gts[96];
    __shared__ float wave_part[4];

    const int tid = threadIdx.x;
    const int b  = blockIdx.x >> 4;   // 16 n-chunks per b
    const int nc = blockIdx.x & 15;

    if (tid < 96) gts[tid] = gt4[b * 96 + tid];
    __syncthreads();

    const float2 p = pred4[b * 4096 + nc * 256 + tid];
    const float s = p.x, e = p.y;

    float acc = 0.0f;  // sum of log2(iou), iou in (0,1] -> acc <= 0
#pragma unroll 8
    for (int t = 0; t < 96; ++t) {
        const float a  = gts[t].x;
        const float bb = gts[t].y;
        const bool c0 = (s < a) && (e > bb);
        const bool c1 = (s < a) && (e < bb) && (e > a);
        const bool c2 = (s > a) && (s < bb) && (e > bb);
        const float num = c0 ? (bb - a) : (c1 ? (e - a) : (bb - s));
        const float den = c0 ? (e - s)  : (c1 ? (bb - s) : (e - a));
        float r = (c0 | c1 | c2) ? (num / den) : 1.0f;
        // reference: iou < EPS (incl. 0 / no-overlap) -> 1.0 -> log = 0.
        // NaN compares false -> also folds to 1.0.
        r = (r >= EPS) ? r : 1.0f;
        acc += __log2f(r);
    }

    // wave (64-lane) butterfly reduce
    for (int off = 32; off; off >>= 1)
        acc += __shfl_down(acc, off);

    const int lane = tid & 63;
    const int wid  = tid >> 6;
    if (lane == 0) wave_part[wid] = acc;
    __syncthreads();

    if (tid == 0) {
        const float total = wave_part[0] + wave_part[1] + wave_part[2] + wave_part[3];
        // loss = -sum(ln(iou)) / batch = -ln2 * sum(log2(iou)) / batch
        const float scale = -0.69314718055994531f / (float)bs_ptr[0];
        atomicAdd(out, total * scale);
    }
}

extern "C" void kernel_launch(void* const* d_in, const int* in_sizes, int n_in,
                              void* d_out, int out_size, void* d_ws, size_t ws_size,
                              hipStream_t stream) {
    (void)in_sizes; (void)n_in; (void)d_ws; (void)ws_size; (void)out_size;

    const float* pred = (const float*)d_in[0];   // (L,B,N,2) f32
    const float* gt   = (const float*)d_in[1];   // (L,B,T,2) f32
    const int*   bs   = (const int*)d_in[2];     // scalar
    float*       out  = (float*)d_out;

    const int L = 5, B = 16, N = 4096, T = 96;
    const float2* pred4 = (const float2*)pred + (size_t)(L - 1) * B * N;  // layer L-1
    const float2* gt4   = (const float2*)gt   + (size_t)(L - 1) * B * T;

    // d_out is poisoned before timing and we accumulate with atomics:
    // zero it on-stream every call (graph-capture-safe).
    hipMemsetAsync(out, 0, sizeof(float), stream);

    iou_loss_kernel<<<dim3(B * 16), dim3(256), 0, stream>>>(pred4, gt4, bs, out);
}

// Round 2
// 14.373 us; speedup vs baseline: 2.0843x; 2.0843x over previous
//
#include <hip/hip_runtime.h>

#define EPS 1e-6f
#define NBLK 1024   // 16 b × 16 n-chunks × 4 t-chunks

__global__ __launch_bounds__(256) void iou_partial_kernel(
    const float2* __restrict__ pred4,  // layer-4 base, (B=16, N=4096) float2
    const float2* __restrict__ gt4,    // layer-4 base, (B=16, T=96) float2
    float* __restrict__ partial)       // [NBLK] in d_ws
{
    __shared__ float2 gts[24];
    __shared__ float wave_part[4];

    const int tid = threadIdx.x;
    const int blk = blockIdx.x;
    const int b  = blk >> 6;          // 64 blocks per b
    const int nc = (blk >> 2) & 15;   // n chunk of 256
    const int tc = blk & 3;           // t chunk of 24

    if (tid < 24) gts[tid] = gt4[b * 96 + tc * 24 + tid];
    __syncthreads();

    const float2 p = pred4[b * 4096 + nc * 256 + tid];
    const float s = p.x, e = p.y;

    float acc = 0.0f;  // sum of log2(iou) over valid pairs
#pragma unroll
    for (int t = 0; t < 24; ++t) {
        const float a  = gts[t].x;
        const float bb = gts[t].y;
        const bool c0 = (s < a) & (e > bb);
        const bool c1 = (s < a) & (e < bb) & (e > a);
        const bool c2 = (s > a) & (s < bb) & (e > bb);
        const float num = c0 ? (bb - a) : (c1 ? (e - a) : (bb - s));
        const float den = c0 ? (e - s)  : (c1 ? (bb - s) : (e - a));
        // conditions mutually exclusive; den > 0 whenever any holds.
        // iou < EPS (incl. no-overlap / num==0) -> reference maps to 1.0 -> log 0.
        const bool valid = (c0 | c1 | c2) && (num >= EPS * den);
        const float contrib = __log2f(num) - __log2f(den);
        acc += valid ? contrib : 0.0f;   // cndmask: NaN from garbage logs never selected
    }

    for (int off = 32; off; off >>= 1)
        acc += __shfl_down(acc, off);
    if ((tid & 63) == 0) wave_part[tid >> 6] = acc;
    __syncthreads();
    if (tid == 0)
        partial[blk] = wave_part[0] + wave_part[1] + wave_part[2] + wave_part[3];
}

__global__ __launch_bounds__(256) void iou_final_kernel(
    const float* __restrict__ partial,
    const int* __restrict__ bs_ptr,
    float* __restrict__ out)
{
    __shared__ float wave_part[4];
    const int tid = threadIdx.x;

    float v = 0.0f;
#pragma unroll
    for (int i = 0; i < NBLK / 256; ++i)
        v += partial[i * 256 + tid];

    for (int off = 32; off; off >>= 1)
        v += __shfl_down(v, off);
    if ((tid & 63) == 0) wave_part[tid >> 6] = v;
    __syncthreads();

    if (tid == 0) {
        const float total = wave_part[0] + wave_part[1] + wave_part[2] + wave_part[3];
        // loss = -sum(ln(iou)) / batch = -ln2 * sum(log2(iou)) / batch
        out[0] = total * (-0.69314718055994531f / (float)bs_ptr[0]);
    }
}

extern "C" void kernel_launch(void* const* d_in, const int* in_sizes, int n_in,
                              void* d_out, int out_size, void* d_ws, size_t ws_size,
                              hipStream_t stream) {
    (void)in_sizes; (void)n_in; (void)ws_size; (void)out_size;

    const float* pred = (const float*)d_in[0];   // (L,B,N,2) f32
    const float* gt   = (const float*)d_in[1];   // (L,B,T,2) f32
    const int*   bs   = (const int*)d_in[2];     // scalar
    float*       out  = (float*)d_out;
    float*       partial = (float*)d_ws;         // NBLK floats

    const int L = 5, B = 16, N = 4096, T = 96;
    const float2* pred4 = (const float2*)pred + (size_t)(L - 1) * B * N;  // layer L-1
    const float2* gt4   = (const float2*)gt   + (size_t)(L - 1) * B * T;

    iou_partial_kernel<<<dim3(NBLK), dim3(256), 0, stream>>>(pred4, gt4, partial);
    iou_final_kernel<<<dim3(1), dim3(256), 0, stream>>>(partial, bs, out);
}